// Round 1
// baseline (149.951 us; speedup 1.0000x reference)
//
#include <hip/hip_runtime.h>
#include <stdint.h>

#define Bb 8
#define Nn 1024
#define Dd 768
#define Hh 12
#define HDd 64
#define Mm (Bb * Nn)      // 8192
#define QKVN (3 * Dd)     // 2304
#define SCALE_F 8.0f      // sqrt(64), multiplies (no softmax in reference)

typedef __attribute__((ext_vector_type(8))) short bf16x8;
typedef __attribute__((ext_vector_type(4))) float f32x4;

__device__ __forceinline__ float bf2f(unsigned short u) {
  unsigned int v = ((unsigned int)u) << 16;
  float f;
  __builtin_memcpy(&f, &v, 4);
  return f;
}
__device__ __forceinline__ unsigned short f2bf(float f) {
  unsigned int u;
  __builtin_memcpy(&u, &f, 4);
  u += 0x7FFFu + ((u >> 16) & 1u);  // round-to-nearest-even
  return (unsigned short)(u >> 16);
}

#define GLDS16(g, l)                                                          \
  __builtin_amdgcn_global_load_lds(                                          \
      (const __attribute__((address_space(1))) void*)(g),                    \
      (__attribute__((address_space(3))) void*)(l), 16, 0, 0)

// ---------------- f32 -> bf16 convert (x, w_qkv, w_fc) ----------------
__global__ void convert_kernel(const float* __restrict__ x,
                               const float* __restrict__ wqkv,
                               const float* __restrict__ wfc,
                               unsigned short* __restrict__ xb,
                               unsigned short* __restrict__ wqkvb,
                               unsigned short* __restrict__ wfcb) {
  const int n1 = Mm * Dd / 4, n2 = QKVN * Dd / 4, n3 = Dd * Dd / 4;
  const int total = n1 + n2 + n3;
  for (int i = blockIdx.x * blockDim.x + threadIdx.x; i < total;
       i += gridDim.x * blockDim.x) {
    const float* src;
    unsigned short* dst;
    int j;
    if (i < n1) {
      src = x; dst = xb; j = i;
    } else if (i < n1 + n2) {
      src = wqkv; dst = wqkvb; j = i - n1;
    } else {
      src = wfc; dst = wfcb; j = i - n1 - n2;
    }
    const float4 v = ((const float4*)src)[j];
    ushort4 o;
    o.x = f2bf(v.x); o.y = f2bf(v.y); o.z = f2bf(v.z); o.w = f2bf(v.w);
    ((ushort4*)dst)[j] = o;
  }
}

// ---------------- bf16 GEMM, C = A * B^T (+bias), m97 structure --------
// A: [M][K] bf16, Bm: [N][K] bf16 (row n holds B^T row -> contiguous K)
// 128x128 tile, BK=32, 4 waves, each wave 64x64 (4x4 of 16x16x32 MFMA)
template <bool BF16OUT>
__global__ __launch_bounds__(256) void gemm_bt(
    const unsigned short* __restrict__ A, const unsigned short* __restrict__ Bm,
    void* __restrict__ Cout, const float* __restrict__ bias, int Ndim, int K) {
  __shared__ unsigned short As[128 * 32];
  __shared__ unsigned short Bs[128 * 32];
  const int tid = threadIdx.x;
  const int lane = tid & 63;
  const int w = tid >> 6;
  const int m0 = blockIdx.y * 128;
  const int n0 = blockIdx.x * 128;
  const int lr = lane >> 2;   // staging: row within 16-row chunk
  const int l4 = lane & 3;    // staging: 8-elem k segment
  const int wr = (w >> 1) * 64, wc = (w & 1) * 64;
  const int fr = lane & 15, fk = lane >> 4;

  f32x4 acc[4][4] = {};

  for (int k0 = 0; k0 < K; k0 += 32) {
    // stage 128x32 A and B tiles: 8 chunks of 1KB each, 2 per wave
#pragma unroll
    for (int i = 0; i < 2; ++i) {
      const int c = w * 2 + i;
      const int row = c * 16 + lr;
      GLDS16(A + (size_t)(m0 + row) * K + k0 + l4 * 8, &As[c * 512]);
      GLDS16(Bm + (size_t)(n0 + row) * K + k0 + l4 * 8, &Bs[c * 512]);
    }
    asm volatile("s_waitcnt vmcnt(0)" ::: "memory");
    __syncthreads();

    bf16x8 a[4], b[4];
#pragma unroll
    for (int mi = 0; mi < 4; ++mi)
      a[mi] = *(const bf16x8*)&As[(wr + mi * 16 + fr) * 32 + fk * 8];
#pragma unroll
    for (int ni = 0; ni < 4; ++ni)
      b[ni] = *(const bf16x8*)&Bs[(wc + ni * 16 + fr) * 32 + fk * 8];
#pragma unroll
    for (int mi = 0; mi < 4; ++mi)
#pragma unroll
      for (int ni = 0; ni < 4; ++ni)
        acc[mi][ni] = __builtin_amdgcn_mfma_f32_16x16x32_bf16(
            a[mi], b[ni], acc[mi][ni], 0, 0, 0);
    __syncthreads();
  }

#pragma unroll
  for (int mi = 0; mi < 4; ++mi) {
#pragma unroll
    for (int ni = 0; ni < 4; ++ni) {
      const int col = n0 + wc + ni * 16 + fr;
      float bv = 0.0f;
      if (!BF16OUT) bv = bias[col];
#pragma unroll
      for (int r = 0; r < 4; ++r) {
        const int row = m0 + wr + mi * 16 + fk * 4 + r;
        const float val = acc[mi][ni][r] + bv;
        if (BF16OUT)
          ((unsigned short*)Cout)[(size_t)row * Ndim + col] = f2bf(val);
        else
          ((float*)Cout)[(size_t)row * Ndim + col] = val;
      }
    }
  }
}

// ---------------- kTv: ktvT[bh][e][d] = sum_j v[b,j,h,e] * k[b,j,h,d] ---
// grid: x = j-chunk (8 x 128 rows), y = bh (96). Atomic f32 accumulation.
__global__ __launch_bounds__(256) void ktv_kernel(
    const unsigned short* __restrict__ qkv, float* __restrict__ ktv) {
  __shared__ unsigned short kls[128 * 64];
  __shared__ unsigned short vls[128 * 64];
  const int bh = blockIdx.y;
  const int bb = bh / Hh, h = bh % Hh;
  const int j0 = blockIdx.x * 128;
  const int tid = threadIdx.x, lane = tid & 63, w = tid >> 6;
  const size_t rowbase = (size_t)(bb * Nn + j0);
#pragma unroll
  for (int i = 0; i < 4; ++i) {
    const int c = w * 4 + i;
    const int row = c * 8 + (lane >> 3);
    const int col = (lane & 7) * 8;
    const size_t g = (rowbase + row) * QKVN + h * HDd + col;
    GLDS16(qkv + g + Dd, &kls[c * 512]);       // k slice
    GLDS16(qkv + g + 2 * Dd, &vls[c * 512]);   // v slice
  }
  asm volatile("s_waitcnt vmcnt(0)" ::: "memory");
  __syncthreads();

  const int e0 = (tid >> 4) * 4, d0 = (tid & 15) * 4;
  float acc[4][4] = {};
  for (int j = 0; j < 128; ++j) {
    const ushort4 kv = *(const ushort4*)&kls[j * 64 + d0];
    const ushort4 vv = *(const ushort4*)&vls[j * 64 + e0];
    const float kf[4] = {bf2f(kv.x), bf2f(kv.y), bf2f(kv.z), bf2f(kv.w)};
    const float vf[4] = {bf2f(vv.x), bf2f(vv.y), bf2f(vv.z), bf2f(vv.w)};
#pragma unroll
    for (int e = 0; e < 4; ++e)
#pragma unroll
      for (int d = 0; d < 4; ++d) acc[e][d] += vf[e] * kf[d];
  }
  float* outp = ktv + (size_t)bh * (HDd * HDd);
#pragma unroll
  for (int e = 0; e < 4; ++e)
#pragma unroll
    for (int d = 0; d < 4; ++d)
      atomicAdd(&outp[(e0 + e) * HDd + (d0 + d)], acc[e][d]);
}

// ---------------- attn out: ao[b,j,h*64+e] = SCALE * q[j]. kTv[.,e] -----
// grid: x = j-tile (8 x 128 rows), y = bh (96). B = ktvT in padded LDS.
__global__ __launch_bounds__(256) void attn_out_kernel(
    const unsigned short* __restrict__ qkv, const float* __restrict__ ktv,
    unsigned short* __restrict__ ao) {
  __shared__ unsigned short bs[64 * 72];  // [e][d] padded +8 (16B, bank-safe)
  const int bh = blockIdx.y;
  const int bb = bh / Hh, h = bh % Hh;
  const int jt = blockIdx.x;
  const int tid = threadIdx.x, lane = tid & 63, w = tid >> 6;
  {
    const int e = tid >> 2, dblk = (tid & 3) * 16;
    const float* src = ktv + (size_t)bh * 4096 + e * 64 + dblk;
#pragma unroll
    for (int q4 = 0; q4 < 4; ++q4) {
      const float4 v = ((const float4*)src)[q4];
      const int basei = e * 72 + dblk + q4 * 4;
      bs[basei + 0] = f2bf(v.x * SCALE_F);
      bs[basei + 1] = f2bf(v.y * SCALE_F);
      bs[basei + 2] = f2bf(v.z * SCALE_F);
      bs[basei + 3] = f2bf(v.w * SCALE_F);
    }
  }
  __syncthreads();

  const int fr = lane & 15, fk = lane >> 4;
  f32x4 acc[2][4] = {};
  const size_t qrow0 = (size_t)(bb * Nn + jt * 128 + w * 32);
#pragma unroll
  for (int kk = 0; kk < 2; ++kk) {
    bf16x8 bfr[4];
#pragma unroll
    for (int ni = 0; ni < 4; ++ni)
      bfr[ni] = *(const bf16x8*)&bs[(ni * 16 + fr) * 72 + kk * 32 + fk * 8];
#pragma unroll
    for (int mi = 0; mi < 2; ++mi) {
      const bf16x8 afr = *(const bf16x8*)(qkv + (qrow0 + mi * 16 + fr) * QKVN +
                                          h * HDd + kk * 32 + fk * 8);
#pragma unroll
      for (int ni = 0; ni < 4; ++ni)
        acc[mi][ni] = __builtin_amdgcn_mfma_f32_16x16x32_bf16(
            afr, bfr[ni], acc[mi][ni], 0, 0, 0);
    }
  }
#pragma unroll
  for (int mi = 0; mi < 2; ++mi)
#pragma unroll
    for (int ni = 0; ni < 4; ++ni)
#pragma unroll
      for (int r = 0; r < 4; ++r) {
        const int row = jt * 128 + w * 32 + mi * 16 + fk * 4 + r;
        const int col = h * HDd + ni * 16 + fr;
        ao[(size_t)(bb * Nn + row) * Dd + col] = f2bf(acc[mi][ni][r]);
      }
}

extern "C" void kernel_launch(void* const* d_in, const int* in_sizes, int n_in,
                              void* d_out, int out_size, void* d_ws,
                              size_t ws_size, hipStream_t stream) {
  const float* x = (const float*)d_in[0];
  const float* wqkv = (const float*)d_in[1];
  const float* wfc = (const float*)d_in[2];
  const float* bfc = (const float*)d_in[3];
  float* out = (float*)d_out;

  char* ws = (char*)d_ws;
  unsigned short* xb    = (unsigned short*)(ws);                // 12.6 MB
  unsigned short* wqkvb = (unsigned short*)(ws + 12582912);     // 3.5 MB
  unsigned short* wfcb  = (unsigned short*)(ws + 16121856);     // 1.2 MB
  unsigned short* qkv   = (unsigned short*)(ws + 17301504);     // 37.7 MB
  float*          ktv   = (float*)(ws + 55050240);              // 1.6 MB
  unsigned short* ao    = (unsigned short*)(ws + 56623104);     // 12.6 MB
  // total 69,206,016 bytes

  hipMemsetAsync(ktv, 0, 96 * 4096 * sizeof(float), stream);
  convert_kernel<<<2112, 256, 0, stream>>>(x, wqkv, wfc, xb, wqkvb, wfcb);
  gemm_bt<true><<<dim3(QKVN / 128, Mm / 128), 256, 0, stream>>>(
      xb, wqkvb, qkv, nullptr, QKVN, Dd);
  ktv_kernel<<<dim3(8, 96), 256, 0, stream>>>(qkv, ktv);
  attn_out_kernel<<<dim3(8, 96), 256, 0, stream>>>(qkv, ktv, ao);
  gemm_bt<false><<<dim3(Dd / 128, Mm / 128), 256, 0, stream>>>(
      ao, wfcb, out, bfc, Dd, Dd);
}